// Round 5
// baseline (228.435 us; speedup 1.0000x reference)
//
#include <hip/hip_runtime.h>
#include <math.h>

#define NPTS 4096
#define NV   3200
#define NF   6240
#define SENT 0xFFFFFFFFFFFFFFFFull

__device__ __forceinline__ float sane(float v) {
    // insurance: never emit NaN/Inf into the output buffer
    return (v == v && fabsf(v) < 1e30f) ? v : 0.0f;
}

// ---------------- Kernel A: KNN + blended normal (one block per point) ----------
// float32 inputs. Each thread: sorted top-8 over ~13 strided vertices as packed
// (d2bits, idx) uint64 keys (exact (d2, idx) lexicographic order -> matches
// lax.top_k stable tie-break). Thread 0 merges (early-break: each group sorted)
// and writes n (float32) to d_out's n-section.
__global__ __launch_bounds__(256) void normals_kernel(
    const float* __restrict__ x_in,
    const float* __restrict__ verts,
    const float* __restrict__ vnorm,
    float* __restrict__ out)     // d_out: [xc 12288][s 4096][n 12288] float32
{
#pragma clang fp contract(off)
    __shared__ unsigned long long keys[256 * 8];   // 16 KB
    const int tid = threadIdx.x;
    const int p   = blockIdx.x;

    const float px = x_in[3 * p + 0];
    const float py = x_in[3 * p + 1];
    const float pz = x_in[3 * p + 2];

    unsigned long long top[8];
#pragma unroll
    for (int k = 0; k < 8; ++k) top[k] = SENT;

    for (int v = tid; v < NV; v += 256) {
        const float dx = px - verts[3 * v + 0];
        const float dy = py - verts[3 * v + 1];
        const float dz = pz - verts[3 * v + 2];
        const float d2 = dx * dx + dy * dy + dz * dz;   // >= 0 -> bits monotone
        const unsigned long long key =
            ((unsigned long long)__float_as_uint(d2) << 32) | (unsigned int)v;
        if (key < top[7]) {
            top[7] = key;
#pragma unroll
            for (int k = 7; k > 0; --k)
                if (top[k] < top[k - 1]) {
                    unsigned long long t = top[k]; top[k] = top[k - 1]; top[k - 1] = t;
                }
        }
    }
#pragma unroll
    for (int k = 0; k < 8; ++k) keys[tid * 8 + k] = top[k];
    __syncthreads();

    if (tid == 0) {
        unsigned long long best[8];
#pragma unroll
        for (int k = 0; k < 8; ++k) best[k] = SENT;
        for (int t2 = 0; t2 < 256; ++t2) {
            for (int k2 = 0; k2 < 8; ++k2) {           // each group sorted ascending
                const unsigned long long key = keys[t2 * 8 + k2];
                if (key >= best[7]) break;             // rest of group can't qualify
                best[7] = key;
#pragma unroll
                for (int k = 7; k > 0; --k)
                    if (best[k] < best[k - 1]) {
                        unsigned long long t = best[k]; best[k] = best[k - 1]; best[k - 1] = t;
                    }
            }
        }

        float tknx = 0.f, tkny = 0.f, tknz = 0.f, Wsum = 0.f;
#pragma unroll
        for (int k = 0; k < 8; ++k) {
            const float d2 = __uint_as_float((unsigned int)(best[k] >> 32));
            const int   vi = (int)(best[k] & 0xFFFFFFFFull);
            const float w  = 1.0f / fmaxf(d2, 1e-8f);
            Wsum += w;
            tknx += vnorm[3 * vi + 0] * w;
            tkny += vnorm[3 * vi + 1] * w;
            tknz += vnorm[3 * vi + 2] * w;
        }
        const int v1 = (int)(best[0] & 0xFFFFFFFFull);
        const float rx = px - verts[3 * v1 + 0];
        const float ry = py - verts[3 * v1 + 1];
        const float rz = pz - verts[3 * v1 + 2];
        const float d2v1 = fmaxf(rx * rx + ry * ry + rz * rz, 1e-8f);
        const float sc = 1.0f / (0.01f * d2v1);
        const float Wt = Wsum + 100.0f;
        const float ntx = (tknx + rx * sc) / Wt;
        const float nty = (tkny + ry * sc) / Wt;
        const float ntz = (tknz + rz * sc) / Wt;
        const float nrm = sqrtf(ntx * ntx + nty * nty + ntz * ntz);
        const float inv = 1.0f / (nrm + 1e-8f);
        out[NPTS * 4 + 3 * p + 0] = sane(ntx * inv);
        out[NPTS * 4 + 3 * p + 1] = sane(nty * inv);
        out[NPTS * 4 + 3 * p + 2] = sane(ntz * inv);
    }
}

// ---------------- Kernel B: raycast (one block per point) -----------------------
// Reads the float32 normal back from d_out (written by kernel A, same stream).
// Each thread tests ~25 strided faces; LDS tree min-reduction; thread 0 writes.
__global__ __launch_bounds__(256) void raycast_kernel(
    const float* __restrict__ x_in,
    const float* __restrict__ verts,
    const int* __restrict__ faces,
    float* __restrict__ out)
{
#pragma clang fp contract(off)
    __shared__ float red[256];                      // 1 KB
    const int tid = threadIdx.x;
    const int p   = blockIdx.x;

    const float px = x_in[3 * p + 0];
    const float py = x_in[3 * p + 1];
    const float pz = x_in[3 * p + 2];
    const float nx = out[NPTS * 4 + 3 * p + 0];
    const float ny = out[NPTS * 4 + 3 * p + 1];
    const float nz = out[NPTS * 4 + 3 * p + 2];
    const float dx = -nx, dy = -ny, dz = -nz;

    float tmin = 3.0e38f;
    for (int f = tid; f < NF; f += 256) {
        const int a = faces[3 * f + 0];
        const int b = faces[3 * f + 1];
        const int c = faces[3 * f + 2];
        const float v0x = verts[3 * a + 0];
        const float v0y = verts[3 * a + 1];
        const float v0z = verts[3 * a + 2];
        const float e1x = verts[3 * b + 0] - v0x;
        const float e1y = verts[3 * b + 1] - v0y;
        const float e1z = verts[3 * b + 2] - v0z;
        const float e2x = verts[3 * c + 0] - v0x;
        const float e2y = verts[3 * c + 1] - v0y;
        const float e2z = verts[3 * c + 2] - v0z;

        const float pvx = dy * e2z - dz * e2y;
        const float pvy = dz * e2x - dx * e2z;
        const float pvz = dx * e2y - dy * e2x;
        const float det = e1x * pvx + e1y * pvy + e1z * pvz;
        const bool ok = fabsf(det) > 1e-9f;
        const float det_s = ok ? det : 1.0f;        // ref: 1/where(ok, det, 1)
        const float invd = ok ? (1.0f / det_s) : 0.0f;
        const float tvx = px - v0x;
        const float tvy = py - v0y;
        const float tvz = pz - v0z;
        const float u = (tvx * pvx + tvy * pvy + tvz * pvz) * invd;
        const float qvx = tvy * e1z - tvz * e1y;
        const float qvy = tvz * e1x - tvx * e1z;
        const float qvz = tvx * e1y - tvy * e1x;
        const float vv = (dx * qvx + dy * qvy + dz * qvz) * invd;
        const float tt = (e2x * qvx + e2y * qvy + e2z * qvz) * invd;
        const bool valid = ok && (u >= -1e-6f) && (vv >= -1e-6f) &&
                           (u + vv <= 1.0f + 1e-6f) && (tt > 1e-6f);
        if (valid) tmin = fminf(tmin, tt);
    }

    red[tid] = tmin;
    __syncthreads();
    for (int s = 128; s > 0; s >>= 1) {
        if (tid < s) red[tid] = fminf(red[tid], red[tid + s]);
        __syncthreads();
    }

    if (tid == 0) {
        const float m = red[0];
        const float t = (m < 1e37f) ? m : 0.0f;     // no hit -> t = 0 (matches ref)
        const float xcx = px - t * nx;
        const float xcy = py - t * ny;
        const float xcz = pz - t * nz;
        const float sdot = (px - xcx) * nx + (py - xcy) * ny + (pz - xcz) * nz;
        out[3 * p + 0] = sane(xcx);
        out[3 * p + 1] = sane(xcy);
        out[3 * p + 2] = sane(xcz);
        out[NPTS * 3 + p] = sane(sdot);
    }
}

extern "C" void kernel_launch(void* const* d_in, const int* in_sizes, int n_in,
                              void* d_out, int out_size, void* d_ws, size_t ws_size,
                              hipStream_t stream) {
    const float* x     = (const float*)d_in[0];
    const float* verts = (const float*)d_in[1];
    const float* vnorm = (const float*)d_in[2];
    const int*   faces = (const int*)d_in[3];
    float* out = (float*)d_out;

    normals_kernel<<<NPTS, 256, 0, stream>>>(x, verts, vnorm, out);
    raycast_kernel<<<NPTS, 256, 0, stream>>>(x, verts, faces, out);
}

// Round 6
// 156.423 us; speedup vs baseline: 1.4604x; 1.4604x over previous
//
#include <hip/hip_runtime.h>
#include <math.h>

#define NPTS 4096
#define NV   3200
#define NF   6240
#define PB   8
#define SLOT 9              // u64 stride per 8-key list (pad: kills 32-way bank alias)
#define SENT 0xFFFFFFFFFFFFFFFFull

__device__ __forceinline__ float sane(float v) {
    return (v == v && fabsf(v) < 1e30f) ? v : 0.0f;
}

// merge two sorted-ascending 8-lists (LDS) -> smallest 8, sorted, into dst (LDS).
// L[i] = min(a[i], b[7-i]) is the lower half of the bitonic concat; 3 half-cleaner
// stages (4,2,1) sort it. All static indexing -> stays in VGPRs.
__device__ __forceinline__ void merge8(const unsigned long long* __restrict__ a,
                                       const unsigned long long* __restrict__ b,
                                       unsigned long long* __restrict__ d) {
    unsigned long long L[8];
#pragma unroll
    for (int i = 0; i < 8; ++i) {
        const unsigned long long x = a[i], y = b[7 - i];
        L[i] = (x < y) ? x : y;
    }
#pragma unroll
    for (int dist = 4; dist >= 1; dist >>= 1) {
#pragma unroll
        for (int i = 0; i < 8; ++i) {
            if ((i & dist) == 0) {
                const unsigned long long lo = L[i], hi = L[i + dist];
                const bool sw = hi < lo;
                L[i]        = sw ? hi : lo;
                L[i + dist] = sw ? lo : hi;
            }
        }
    }
#pragma unroll
    for (int i = 0; i < 8; ++i) d[i] = L[i];
}

// ---------------- Kernel A: KNN + blended normal ------------------------------
// grid 1024 x 256: wave w of block handles point blockIdx.x*4+w.
// Each lane: sorted top-8 over 50 verts as packed (d2bits<<32)|idx keys
// (exact (d2, idx) lexicographic == lax.top_k tie-break).
// Then 6-level parallel bitonic merge tree in LDS (64 lists -> 1).
__global__ __launch_bounds__(256) void normals_kernel(
    const float* __restrict__ x_in,
    const float* __restrict__ verts,
    const float* __restrict__ vnorm,
    float* __restrict__ out)     // d_out: [xc 12288][s 4096][n 12288] fp32
{
#pragma clang fp contract(off)
    __shared__ unsigned long long bufA[4 * 64 * SLOT];   // 18.4 KB
    __shared__ unsigned long long bufB[4 * 32 * SLOT];   //  9.2 KB
    const int tid  = threadIdx.x;
    const int wid  = tid >> 6;
    const int lane = tid & 63;
    const int p    = blockIdx.x * 4 + wid;

    const float px = x_in[3 * p + 0];
    const float py = x_in[3 * p + 1];
    const float pz = x_in[3 * p + 2];

    unsigned long long top[8];
#pragma unroll
    for (int k = 0; k < 8; ++k) top[k] = SENT;

    for (int j = 0; j < NV / 64; ++j) {
        const int v = lane + (j << 6);
        const float dx = px - verts[3 * v + 0];
        const float dy = py - verts[3 * v + 1];
        const float dz = pz - verts[3 * v + 2];
        const float d2 = dx * dx + dy * dy + dz * dz;
        const unsigned long long key =
            ((unsigned long long)__float_as_uint(d2) << 32) | (unsigned int)v;
        if (key < top[7]) {
            top[7] = key;
#pragma unroll
            for (int k = 7; k > 0; --k)
                if (top[k] < top[k - 1]) {
                    unsigned long long t = top[k]; top[k] = top[k - 1]; top[k - 1] = t;
                }
        }
    }

    unsigned long long* __restrict__ A = bufA + wid * 64 * SLOT;
    unsigned long long* __restrict__ B = bufB + wid * 32 * SLOT;
#pragma unroll
    for (int k = 0; k < 8; ++k) A[lane * SLOT + k] = top[k];
    __syncthreads();

    // 64 -> 32 -> 16 -> 8 -> 4 -> 2 -> 1 ; src alternates A,B,A,... final in A[0..7]
    int n = 64;
    bool srcA = true;
    while (n > 1) {
        const int half = n >> 1;
        if (lane < half) {
            const unsigned long long* s = srcA ? A : B;
            unsigned long long*       d = srcA ? B : A;
            merge8(s + (2 * lane) * SLOT, s + (2 * lane + 1) * SLOT, d + lane * SLOT);
        }
        __syncthreads();
        srcA = !srcA;
        n = half;
    }

    if (lane == 0) {
        float tknx = 0.f, tkny = 0.f, tknz = 0.f, Wsum = 0.f;
#pragma unroll
        for (int k = 0; k < 8; ++k) {
            const unsigned long long key = A[k];
            const float d2 = __uint_as_float((unsigned int)(key >> 32));
            const int   vi = (int)(key & 0xFFFFFFFFull);
            const float w  = 1.0f / fmaxf(d2, 1e-8f);
            Wsum += w;
            tknx += vnorm[3 * vi + 0] * w;
            tkny += vnorm[3 * vi + 1] * w;
            tknz += vnorm[3 * vi + 2] * w;
        }
        const int v1 = (int)(A[0] & 0xFFFFFFFFull);
        const float rx = px - verts[3 * v1 + 0];
        const float ry = py - verts[3 * v1 + 1];
        const float rz = pz - verts[3 * v1 + 2];
        const float d2v1 = fmaxf(rx * rx + ry * ry + rz * rz, 1e-8f);
        const float sc = 1.0f / (0.01f * d2v1);
        const float Wt = Wsum + 100.0f;
        const float ntx = (tknx + rx * sc) / Wt;
        const float nty = (tkny + ry * sc) / Wt;
        const float ntz = (tknz + rz * sc) / Wt;
        const float nrm = sqrtf(ntx * ntx + nty * nty + ntz * ntz);
        const float inv = 1.0f / (nrm + 1e-8f);
        out[NPTS * 4 + 3 * p + 0] = sane(ntx * inv);
        out[NPTS * 4 + 3 * p + 1] = sane(nty * inv);
        out[NPTS * 4 + 3 * p + 2] = sane(ntz * inv);
    }
}

// ---------------- Kernel B: raycast, 8 points/block ---------------------------
// Each thread owns ~24 strided faces; per face the 12 gathered values are tested
// against all 8 points held in registers. LDS tree min-reduction per point.
__global__ __launch_bounds__(256) void raycast_kernel(
    const float* __restrict__ x_in,
    const float* __restrict__ verts,
    const int* __restrict__ faces,
    float* __restrict__ out)
{
#pragma clang fp contract(off)
    __shared__ float sx[PB][3];
    __shared__ float sn[PB][3];
    __shared__ float red[PB * 256];     // 8 KB
    const int tid = threadIdx.x;
    const int p0  = blockIdx.x * PB;

    if (tid < PB * 3) {
        const int p = tid / 3, c = tid % 3;
        sx[p][c] = x_in[(p0 + p) * 3 + c];
        sn[p][c] = out[NPTS * 4 + (p0 + p) * 3 + c];   // fp32 normal from kernel A
    }
    __syncthreads();

    float qx[PB], qy[PB], qz[PB], dx[PB], dy[PB], dz[PB];
#pragma unroll
    for (int p = 0; p < PB; ++p) {
        qx[p] = sx[p][0]; qy[p] = sx[p][1]; qz[p] = sx[p][2];
        dx[p] = -sn[p][0]; dy[p] = -sn[p][1]; dz[p] = -sn[p][2];
    }

    float tmin[PB];
#pragma unroll
    for (int p = 0; p < PB; ++p) tmin[p] = 3.0e38f;

    for (int f = tid; f < NF; f += 256) {
        const int a = faces[3 * f + 0];
        const int b = faces[3 * f + 1];
        const int c = faces[3 * f + 2];
        const float v0x = verts[3 * a + 0];
        const float v0y = verts[3 * a + 1];
        const float v0z = verts[3 * a + 2];
        const float e1x = verts[3 * b + 0] - v0x;
        const float e1y = verts[3 * b + 1] - v0y;
        const float e1z = verts[3 * b + 2] - v0z;
        const float e2x = verts[3 * c + 0] - v0x;
        const float e2y = verts[3 * c + 1] - v0y;
        const float e2z = verts[3 * c + 2] - v0z;
#pragma unroll
        for (int p = 0; p < PB; ++p) {
            const float pvx = dy[p] * e2z - dz[p] * e2y;
            const float pvy = dz[p] * e2x - dx[p] * e2z;
            const float pvz = dx[p] * e2y - dy[p] * e2x;
            const float det = e1x * pvx + e1y * pvy + e1z * pvz;
            const bool ok = fabsf(det) > 1e-9f;
            const float det_s = ok ? det : 1.0f;
            const float invd = ok ? (1.0f / det_s) : 0.0f;
            const float tvx = qx[p] - v0x;
            const float tvy = qy[p] - v0y;
            const float tvz = qz[p] - v0z;
            const float u = (tvx * pvx + tvy * pvy + tvz * pvz) * invd;
            const float qvx = tvy * e1z - tvz * e1y;
            const float qvy = tvz * e1x - tvx * e1z;
            const float qvz = tvx * e1y - tvy * e1x;
            const float vv = (dx[p] * qvx + dy[p] * qvy + dz[p] * qvz) * invd;
            const float tt = (e2x * qvx + e2y * qvy + e2z * qvz) * invd;
            const bool valid = ok && (u >= -1e-6f) && (vv >= -1e-6f) &&
                               (u + vv <= 1.0f + 1e-6f) && (tt > 1e-6f);
            if (valid) tmin[p] = fminf(tmin[p], tt);
        }
    }

#pragma unroll
    for (int p = 0; p < PB; ++p) red[p * 256 + tid] = tmin[p];

    for (int s = 128; s > 0; s >>= 1) {
        __syncthreads();
        if (tid < s) {
#pragma unroll
            for (int p = 0; p < PB; ++p)
                red[p * 256 + tid] = fminf(red[p * 256 + tid], red[p * 256 + tid + s]);
        }
    }
    __syncthreads();

    if (tid < PB) {
        const int p = tid;
        const float m = red[p * 256];
        const float t = (m < 1e37f) ? m : 0.0f;     // no hit -> t = 0 (matches ref)
        const float px = sx[p][0], py = sx[p][1], pz = sx[p][2];
        const float nx = sn[p][0], ny = sn[p][1], nz = sn[p][2];
        const float xcx = px - t * nx;
        const float xcy = py - t * ny;
        const float xcz = pz - t * nz;
        const float sdot = (px - xcx) * nx + (py - xcy) * ny + (pz - xcz) * nz;
        const int gp = p0 + p;
        out[3 * gp + 0] = sane(xcx);
        out[3 * gp + 1] = sane(xcy);
        out[3 * gp + 2] = sane(xcz);
        out[NPTS * 3 + gp] = sane(sdot);
    }
}

extern "C" void kernel_launch(void* const* d_in, const int* in_sizes, int n_in,
                              void* d_out, int out_size, void* d_ws, size_t ws_size,
                              hipStream_t stream) {
    const float* x     = (const float*)d_in[0];
    const float* verts = (const float*)d_in[1];
    const float* vnorm = (const float*)d_in[2];
    const int*   faces = (const int*)d_in[3];
    float* out = (float*)d_out;

    normals_kernel<<<NPTS / 4, 256, 0, stream>>>(x, verts, vnorm, out);
    raycast_kernel<<<NPTS / PB, 256, 0, stream>>>(x, verts, faces, out);
}